// Round 15
// baseline (528.627 us; speedup 1.0000x reference)
//
#include <hip/hip_runtime.h>
#include <hip/hip_bf16.h>
#include <math.h>

typedef __hip_bfloat16 bf16;
typedef short s8v __attribute__((ext_vector_type(8)));
typedef float f4v __attribute__((ext_vector_type(4)));
#define MFMA16(a,b,c) __builtin_amdgcn_mfma_f32_16x16x32_bf16(a,b,c,0,0,0)

// ---------------- problem constants ----------------
#define B2   2
#define C64  64
#define C3   192
#define HEADS 6
#define NWIN 2048   // 2 * 32 * 32 windows

// ---------------- param table offsets (floats) ----------------
#define P_NORMW 0
#define P_NORMB 192
#define P_QKVW  384
#define P_QKVB  110976
#define P_PROJW 111552
#define P_PROJB 148416
#define P_RPB   148608
#define P_AUXDW 149958
#define P_AUXPW 150534
#define P_CG1   154630
#define P_CG2   157702
#define P_PO    166918
#define P_GM    171014
#define P_GA    171015
#define P_GC    171016

// ---------------- workspace byte offsets ----------------
#define WS_FLAG   0
#define WS_PARAMS 256
#define WS_GAP    684544
#define WS_AMUL   685568
#define WS_CVAL   687616
#define WS_TSTAT  689664                   // float2 [2048*64]
#define WS_LL     1738240                  // bf16 [2][64][256][256]
#define WS_DLLW   18515456                 // bf16 [2048][64][64]  (window layout)
#define WS_WOUT   35292672                 // bf16 [2048][64][192]
#define WS_HRAW   85624320                 // bf16 [2048][64][192]
#define WS_WQKV   135955968                // bf16 [576][192]  (LN-folded)
#define WS_WPROJ  136177152                // bf16 [192][192]
#define WS_WPW    136250880                // bf16 [64][64]
#define WS_WPO    136259072                // bf16 [64][64]
#define WS_S12    136267264                // float2 [576] (s1, s2+bias)
#define WS_BIAS6  136271872                // f32 [6][64col][64row] (transposed)
// end = 136,370,176  (< 168.5 MB proven)

// ---------------- helpers ----------------
__device__ __forceinline__ float bfu(unsigned short u){
  return __uint_as_float(((unsigned)u) << 16);
}
__device__ __forceinline__ float LDR(const void* p, long i, bool isf){
  return isf ? ((const float*)p)[i] : bfu(((const unsigned short*)p)[i]);
}
template<bool ISF>
__device__ __forceinline__ float4 LD4(const void* p, long i){   // elems i..i+3 (i%4==0 fp32)
  if constexpr (ISF) return *(const float4*)((const float*)p + i);
  else {
    const ushort4 u = *(const ushort4*)((const bf16*)p + i);
    float4 r; r.x = bfu(u.x); r.y = bfu(u.y); r.z = bfu(u.z); r.w = bfu(u.w);
    return r;
  }
}
template<bool ISF>
__device__ __forceinline__ void ST(void* p, long i, float v){
  if constexpr (ISF) ((float*)p)[i] = v;
  else ((bf16*)p)[i] = __float2bfloat16(v);
}
__device__ __forceinline__ float gelu_f(float x){
  const float z = 0.7978845608028654f * (x + 0.044715f * x*x*x);
  const float t = 1.f - 2.f / (__expf(2.f*z) + 1.f);
  return 0.5f * x * (1.f + t);
}
__device__ __forceinline__ unsigned pk2(float a, float b){
  return (unsigned)__bfloat16_as_ushort(__float2bfloat16(a)) |
         ((unsigned)__bfloat16_as_ushort(__float2bfloat16(b)) << 16);
}
__device__ __forceinline__ uint4 pk8(const float* v){
  uint4 r;
  r.x = pk2(v[0], v[1]); r.y = pk2(v[2], v[3]);
  r.z = pk2(v[4], v[5]); r.w = pk2(v[6], v[7]);
  return r;
}
// async global->LDS 16B DMA: dest = wave-uniform base + lane*16
__device__ __forceinline__ void gld16(const void* g, void* l){
  __builtin_amdgcn_global_load_lds(
      (const __attribute__((address_space(1))) void*)g,
      (__attribute__((address_space(3))) void*)l, 16, 0, 0);
}

// ---------------- K0a: dtype detect ----------------
__global__ __launch_bounds__(256) void detect_kernel(const void* x, int* flag){
  __shared__ int wildcnt;
  if (threadIdx.x == 0) wildcnt = 0;
  __syncthreads();
  const unsigned short* u = (const unsigned short*)x;
  int wild = 0;
  for (int i = threadIdx.x; i < 2048; i += 256){
    unsigned int v = ((unsigned int)u[i]) << 16;
    float f = __uint_as_float(v);
    float a = fabsf(f);
    if (!(a < 1e8f) || (a > 0.f && a < 1e-8f)) wild++;
  }
  atomicAdd(&wildcnt, wild);
  __syncthreads();
  if (threadIdx.x == 0) *flag = (wildcnt > 100) ? 1 : 0;  // 1 = fp32 underlying
}

// ---------------- KPREP: param convert + all weight tables (one launch) ----------------
struct PP { const void* src[15]; float* dst[15]; int n[15]; };
__global__ __launch_bounds__(256) void kprep(PP pp, const int* flag, const int* rpi,
                                             bf16* wqkvF, bf16* wproj, bf16* wpw,
                                             bf16* wpo, float* bias6T, float2* s12p){
  const bool isf = (*flag) != 0;
  const int gid = blockIdx.x*256 + threadIdx.x;
  const int gsz = gridDim.x*256;
  // 1. param table -> pf (f32)
#pragma unroll
  for (int q = 0; q < 15; q++){
    const int n = pp.n[q];
    const void* s = pp.src[q];
    float* d = pp.dst[q];
    for (int i = gid; i < n; i += gsz) d[i] = LDR(s, i, isf);
  }
  // 2. LN-folded qkv weights (bf16)
  const void* qkvw = pp.src[2];
  const void* normw = pp.src[0];
  for (int i = gid; i < 110592; i += gsz)
    wqkvF[i] = __float2bfloat16(LDR(qkvw, i, isf) * LDR(normw, i % 192, isf));
  // 3. proj / pw / po weights (bf16)
  for (int i = gid; i < 36864; i += gsz)
    wproj[i] = __float2bfloat16(LDR(pp.src[4], i, isf));
  for (int i = gid; i < 4096; i += gsz){
    wpw[i] = __float2bfloat16(LDR(pp.src[8], i, isf));
    wpo[i] = __float2bfloat16(LDR(pp.src[11], i, isf));
  }
  // 4. transposed bias table
  for (int j = gid; j < 24576; j += gsz){
    const int hh = j >> 12, nm = j & 4095;
    const int row = nm >> 6, col = nm & 63;
    bias6T[hh*4096 + col*64 + row] = LDR(pp.src[6], rpi[nm]*6 + hh, isf);
  }
  // 5. rank-1 LN correction
  if (gid < 576){
    float s1 = 0.f, s2 = 0.f;
    for (int c = 0; c < 192; ++c){
      const float w = LDR(qkvw, gid*192 + c, isf);
      s1 += w * LDR(normw, c, isf);
      s2 += w * LDR(pp.src[1], c, isf);
    }
    float2 v; v.x = s1; v.y = s2 + LDR(pp.src[3], gid, isf);
    s12p[gid] = v;
  }
}

// ---------------- K1f: single-pass DWT (16B loads) -> ll + hraw + tstat ----------------
template<bool ISF>
__device__ void k1f_body(const void* xv, bf16* llb, bf16* hraw, float2* tstat){
  const int wid = blockIdx.x;
  const int b  = wid >> 10;
  const int wh = (wid >> 5) & 31;
  const int ww = wid & 31;
  const int tid = threadIdx.x;
  const int tp = tid >> 3, l8 = tid & 7;   // token pair 0..31, channel group 0..7
  const int t0 = tp*2;
  const int wi = t0 >> 3, wj0 = t0 & 7;    // wj0 even
  const int h2 = (wh*8 + wi + 4) & 255;
  const int w2 = (ww*8 + wj0 + 4) & 255;   // even
  const long rowbase = ((long)(2*h2) << 9) + 2*w2;
  float r0[3][8], r1[3][8];
  float s0 = 0.f, q0 = 0.f, s1 = 0.f, q1 = 0.f;
#pragma unroll
  for (int cc = 0; cc < 8; ++cc){
    const int c = l8*8 + cc;
    const long base = ((long)(b*64 + c) << 18) + rowbase;
    const float4 ta = LD4<ISF>(xv, base);        // a0,cr0,a1,cr1
    const float4 tb = LD4<ISF>(xv, base + 512);  // bb0,dd0,bb1,dd1
    float a = ta.x, cr = ta.y, bb = tb.x, dd = tb.y;
    const float ll0 = 0.5f*(a + bb + cr + dd);
    const float h00 = 0.5f*(-a - bb + cr + dd);
    const float h10 = 0.5f*(-a + bb - cr + dd);
    const float h20 = 0.5f*( a - bb - cr + dd);
    r0[0][cc] = h00; r0[1][cc] = h10; r0[2][cc] = h20;
    s0 += h00 + h10 + h20; q0 += h00*h00 + h10*h10 + h20*h20;
    a = ta.z; cr = ta.w; bb = tb.z; dd = tb.w;
    const float ll1 = 0.5f*(a + bb + cr + dd);
    const float h01 = 0.5f*(-a - bb + cr + dd);
    const float h11 = 0.5f*(-a + bb - cr + dd);
    const float h21 = 0.5f*( a - bb - cr + dd);
    r1[0][cc] = h01; r1[1][cc] = h11; r1[2][cc] = h21;
    s1 += h01 + h11 + h21; q1 += h01*h01 + h11*h11 + h21*h21;
    *(unsigned*)(llb + ((long)(b*64 + c) << 16) + ((long)h2 << 8) + w2) = pk2(ll0, ll1);
  }
  const long hb = ((long)wid*64 + t0)*192 + l8*8;
  *(uint4*)(hraw + hb)            = pk8(r0[0]);
  *(uint4*)(hraw + hb + 64)       = pk8(r0[1]);
  *(uint4*)(hraw + hb + 128)      = pk8(r0[2]);
  *(uint4*)(hraw + hb + 192)      = pk8(r1[0]);
  *(uint4*)(hraw + hb + 192 + 64) = pk8(r1[1]);
  *(uint4*)(hraw + hb + 192 +128) = pk8(r1[2]);
  s0 += __shfl_xor(s0,1,8); s0 += __shfl_xor(s0,2,8); s0 += __shfl_xor(s0,4,8);
  q0 += __shfl_xor(q0,1,8); q0 += __shfl_xor(q0,2,8); q0 += __shfl_xor(q0,4,8);
  s1 += __shfl_xor(s1,1,8); s1 += __shfl_xor(s1,2,8); s1 += __shfl_xor(s1,4,8);
  q1 += __shfl_xor(q1,1,8); q1 += __shfl_xor(q1,2,8); q1 += __shfl_xor(q1,4,8);
  if (l8 == 0){
    float mean = s0 * (1.f/192.f);
    float var = fmaxf(q0 * (1.f/192.f) - mean*mean, 0.f);
    float rstd = rsqrtf(var + 1e-6f);
    float2 st; st.x = rstd; st.y = mean * rstd;
    tstat[wid*64 + t0] = st;
    mean = s1 * (1.f/192.f);
    var = fmaxf(q1 * (1.f/192.f) - mean*mean, 0.f);
    rstd = rsqrtf(var + 1e-6f);
    st.x = rstd; st.y = mean * rstd;
    tstat[wid*64 + t0 + 1] = st;
  }
}
__global__ __launch_bounds__(256,4) void k1f_dwt(const void* xv, bf16* llb, bf16* hraw,
                                                 float2* tstat, const int* flag){
  if (*flag) k1f_body<true>(xv, llb, hraw, tstat);
  else       k1f_body<false>(xv, llb, hraw, tstat);
}

// ---------------- K3: cross MLP ----------------
__global__ __launch_bounds__(256) void k3_cross(const float* pf, const float* gap,
                                                float* amul, float* cval){
  __shared__ float t1[B2][48];
  __shared__ float g[B2][64];
  const int tid = threadIdx.x;
  if (tid < 128) g[tid >> 6][tid & 63] = gap[tid];
  __syncthreads();
  if (tid < 96){
    const int b = tid / 48, j = tid % 48;
    float s = 0.f;
    const float* w = pf + P_CG1 + j * 64;
    for (int c = 0; c < 64; ++c) s += w[c] * g[b][c];
    t1[b][j] = gelu_f(s);
  }
  __syncthreads();
  const float gm = pf[P_GM], gc = pf[P_GC];
  for (int o = tid; o < B2 * C3; o += 256){
    const int b = o / C3, ch = o % C3;
    float s = 0.f;
    const float* w = pf + P_CG2 + ch * 48;
    for (int j = 0; j < 48; ++j) s += w[j] * t1[b][j];
    const float cr = 1.f / (1.f + expf(-s));
    const float c = gc * (cr - 0.5f) * 2.f;
    cval[o] = c;
    amul[o] = gm * (1.f + c);
  }
}

// ================= KMIX: interleaved k4 attention + k6f aux-conv + k2 gap =================
__device__ void k4_body(char* sm, int g, const bf16* hraw, const float2* tstat,
                        const bf16* wqkvF, const float2* s12p, const float* bias6T,
                        bf16* wout){
  bf16* bstage = (bf16*)sm;
  const int xcd = g & 7, slot = g >> 3;
  const int pair = (slot/6)*8 + xcd;
  const int h    = slot - (slot/6)*6;
  const int tid = threadIdx.x;
  const int wv5 = tid >> 6;             // 0..7
  const int lw  = wv5 >> 2;             // local window
  const int rg  = wv5 & 3;              // row group
  const int l = tid & 63, lr = l & 15, lg = l >> 4;
  const int wid = pair*2 + lw;
  char* reg = sm + 36864 + lw*13312;
  bf16* bq = (bf16*)reg;
  bf16* bk = (bf16*)(reg + 4608);
  char* vtb = reg + 9216;
  bf16* bp = (bf16*)reg;
  const f4v fz = {0.f,0.f,0.f,0.f};
  const float scale = 0.17677669529663687f;
  const bf16* at = hraw + (long)wid * 12288;

#pragma unroll
  for (int pass = 0; pass < 5; ++pass){
    if (pass*512 + wv5*64 < 2304){
      const int idx = pass*512 + tid;
      const int rl  = idx / 24;
      const int off = (idx - rl*24) * 16;
      const int soff = off ^ ((rl & 7) << 4);
      const int grow = (rl >> 5)*192 + h*32 + (rl & 31);
      gld16(wqkvF + grow*192 + (soff >> 1),
            (char*)bstage + (pass*512 + wv5*64)*16);
    }
  }
  s8v aA[6];
#pragma unroll
  for (int ks = 0; ks < 6; ++ks)
    aA[ks] = *(const s8v*)(at + (rg*16+lr)*192 + ks*32 + lg*8);
  float2 st4[4];
#pragma unroll
  for (int i = 0; i < 4; ++i)
    st4[i] = tstat[wid*64 + rg*16 + lg*4 + i];
  __syncthreads();

  f4v acc[6];
#pragma unroll
  for (int nt = 0; nt < 6; ++nt) acc[nt] = fz;
#pragma unroll
  for (int ks = 0; ks < 6; ++ks){
    const int kb = (ks*32 + lg*8) * 2;
#pragma unroll
    for (int nt = 0; nt < 6; ++nt){
      const int row = nt*16 + lr;
      const s8v bfr = *(const s8v*)((const char*)bstage + row*384 + (kb ^ ((row&7)<<4)));
      acc[nt] = MFMA16(aA[ks], bfr, acc[nt]);
    }
  }
#pragma unroll
  for (int nt = 0; nt < 6; ++nt){
    const int ol = nt*16 + lr;
    const int p = ol >> 5, c = ol & 31;
    const int ocol = p*192 + h*32 + c;
    const float2 sp = s12p[ocol];
#pragma unroll
    for (int i = 0; i < 4; ++i){
      const int row = rg*16 + lg*4 + i;
      const float v = st4[i].x*acc[nt][i] - st4[i].y*sp.x + sp.y;
      if (p == 0)      bq[row*36 + c] = __float2bfloat16(v*scale);
      else if (p == 1) bk[row*36 + c] = __float2bfloat16(v);
      else             *(bf16*)(vtb + ((c*128 + row*2) ^ ((c&7)<<4))) = __float2bfloat16(v);
    }
  }
  __syncthreads();

  f4v bld[4];
#pragma unroll
  for (int nt = 0; nt < 4; ++nt)
    bld[nt] = *(const f4v*)(bias6T + h*4096 + (nt*16+lr)*64 + rg*16 + lg*4);
  f4v sacc[4];
  {
    const s8v a = *(const s8v*)(bq + (rg*16+lr)*36 + lg*8);
#pragma unroll
    for (int nt = 0; nt < 4; ++nt){
      const s8v bfr = *(const s8v*)(bk + (nt*16+lr)*36 + lg*8);
      sacc[nt] = MFMA16(a, bfr, bld[nt]);   // bias folded into C operand
    }
  }
  float pvv[4][4];
  float inv4[4];
#pragma unroll
  for (int i = 0; i < 4; ++i){
    float s = 0.f;
#pragma unroll
    for (int nt = 0; nt < 4; ++nt){
      const float e = __expf(sacc[nt][i]);
      pvv[i][nt] = e;
      s += e;
    }
    s += __shfl_xor(s, 1, 16);
    s += __shfl_xor(s, 2, 16);
    s += __shfl_xor(s, 4, 16);
    s += __shfl_xor(s, 8, 16);
    inv4[i] = 1.f/s;
  }
  __syncthreads();

#pragma unroll
  for (int i = 0; i < 4; ++i){
    const int row = rg*16 + lg*4 + i;
#pragma unroll
    for (int nt = 0; nt < 4; ++nt)
      bp[row*72 + nt*16 + lr] = __float2bfloat16(pvv[i][nt]);
  }
  f4v oacc[2] = {fz, fz};
#pragma unroll
  for (int ks2 = 0; ks2 < 2; ++ks2){
    const s8v a = *(const s8v*)(bp + (rg*16+lr)*72 + ks2*32 + lg*8);
#pragma unroll
    for (int nn = 0; nn < 2; ++nn){
      const int d = nn*16 + lr;
      const s8v bfr = *(const s8v*)(vtb + ((d*128 + (ks2*32+lg*8)*2) ^ ((d&7)<<4)));
      oacc[nn] = MFMA16(a, bfr, oacc[nn]);
    }
  }
#pragma unroll
  for (int nn = 0; nn < 2; ++nn)
#pragma unroll
    for (int i = 0; i < 4; ++i){
      const int row = rg*16 + lg*4 + i;
      wout[((long)wid*64 + row)*192 + h*32 + nn*16 + lr] =
        __float2bfloat16(oacc[nn][i] * inv4[i]);
    }
}

__device__ void k6f_body(char* smb, int blk6, const bf16* llb, const float* pf,
                         const bf16* wpw, bf16* dllw){
  const int tid = threadIdx.x;
  const int sub = tid >> 8;              // 0..1
  const int t2 = tid & 255;
  char* sm6 = smb + sub*24576;
  bf16* tile = (bf16*)sm6;               // [64][10][12]
  bf16* t    = (bf16*)(sm6 + 15360);     // [64][72]
  const int tl = blk6*2 + sub;
  const int b = tl >> 10, ti = (tl >> 5) & 31, tj = tl & 31;
  const int y0 = ti*8 - 1;
  const int x0 = tj*8 - 2;

  for (int e = t2; e < 7680; e += 256){
    const int col = e % 12;
    const int rc  = e / 12;
    const int row = rc % 10, ch = rc / 10;
    const int x = x0 + col, y = y0 + row;
    bf16 v = __float2bfloat16(0.f);
    if ((unsigned)x < 256u && (unsigned)y < 256u)
      v = llb[((long)(b*64 + ch) << 16) + ((long)y << 8) + x];
    tile[rc*12 + col] = v;
  }
  __syncthreads();

  {
    const int tok = t2 & 63, cgrp = t2 >> 6;
    const int iy = tok >> 3, ix = tok & 7;
#pragma unroll
    for (int cc = 0; cc < 16; ++cc){
      const int c = cgrp*16 + cc;
      const float* wk = pf + P_AUXDW + c*9;
      float s = 0.f;
#pragma unroll
      for (int ky = 0; ky < 3; ++ky)
#pragma unroll
        for (int kx = 0; kx < 3; ++kx)
          s += wk[ky*3 + kx] * __bfloat162float(tile[(c*10 + iy + ky)*12 + ix + 1 + kx]);
      t[tok*72 + c] = __float2bfloat16(gelu_f(s));
    }
  }
  __syncthreads();

  const int wv = t2 >> 6, l = t2 & 63, lr = l & 15, lg = l >> 4;
  const f4v fz = {0.f,0.f,0.f,0.f};
  f4v acc[4];
#pragma unroll
  for (int nt = 0; nt < 4; ++nt) acc[nt] = fz;
#pragma unroll
  for (int ks = 0; ks < 2; ++ks){
    const s8v a = *(const s8v*)(t + (wv*16+lr)*72 + ks*32 + lg*8);
#pragma unroll
    for (int nt = 0; nt < 4; ++nt){
      const s8v bfr = *(const s8v*)(wpw + (nt*16+lr)*64 + ks*32 + lg*8);
      acc[nt] = MFMA16(a, bfr, acc[nt]);
    }
  }
  const float ga = pf[P_GA];
#pragma unroll
  for (int i = 0; i < 4; ++i){
    const int p = wv*16 + lg*4 + i;
    const int y = ti*8 + (p >> 3), x = tj*8 + (p & 7);
    const int sy = (y - 4) & 255, sx = (x - 4) & 255;
    const int wd = b*1024 + (sy >> 3)*32 + (sx >> 3);
    const int tok2 = (sy & 7)*8 + (sx & 7);
    const long ob = ((long)wd*64 + tok2)*64;
#pragma unroll
    for (int nt = 0; nt < 4; ++nt)
      dllw[ob + nt*16 + lr] = __float2bfloat16(ga * acc[nt][i]);
  }
}

__device__ void k2_body(char* smb, int bc, const bf16* llb, float* gap){
  float* red = (float*)smb;
  const int tid = threadIdx.x;
  const uint4* p = (const uint4*)(llb + ((long)bc << 16));
  float s = 0.f;
  for (int i = tid; i < 8192; i += 512){
    const uint4 v = p[i];
    s += __uint_as_float(v.x << 16) + __uint_as_float(v.x & 0xffff0000u);
    s += __uint_as_float(v.y << 16) + __uint_as_float(v.y & 0xffff0000u);
    s += __uint_as_float(v.z << 16) + __uint_as_float(v.z & 0xffff0000u);
    s += __uint_as_float(v.w << 16) + __uint_as_float(v.w & 0xffff0000u);
  }
  red[tid] = s; __syncthreads();
  for (int st = 256; st > 0; st >>= 1){
    if (tid < st) red[tid] += red[tid + st];
    __syncthreads();
  }
  if (tid == 0) gap[bc] = red[0] * (1.f / 65536.f);
}

__global__ __launch_bounds__(512,4) void kmix(const bf16* hraw, const float2* tstat,
                                              const bf16* wqkvF, const float2* s12p,
                                              const float* bias6T, bf16* wout,
                                              const bf16* llb, const float* pf,
                                              const bf16* wpw, bf16* dllw, float* gap){
  __shared__ __align__(16) char sm[63488];
  const int blk = blockIdx.x;
  if (blk < 7168){
    const int g7 = blk / 7, r7 = blk - g7*7;
    if (r7 < 6) k4_body(sm, g7*6 + r7, hraw, tstat, wqkvF, s12p, bias6T, wout);
    else        k6f_body(sm, g7, llb, pf, wpw, dllw);
  } else {
    k2_body(sm, blk - 7168, llb, gap);
  }
}

// ---------------- K57: proj + combine + IWT + out-conv, fused ----------------
// block = (b, output row hh, half). 128 token rows in 2 chunks of 64.
// LDS: yp [256px][64ch] swizzled @0 (32768); hstage [64][192] row-swizzled @32768 (24576)
template<bool ISF>
__device__ void k57_body(const bf16* wout, const bf16* hraw, const bf16* dllw,
                         const bf16* wproj, const bf16* wpo, const float* pf,
                         const float* amul, const float* cval, void* out, char* sm){
  char* ypb = sm;
  bf16* hst = (bf16*)(sm + 32768);
  const int blk = blockIdx.x;
  const int b = blk >> 10, hh = (blk >> 1) & 511, half = blk & 1;
  const int h2 = hh >> 1, posH = hh & 1;
  const int th = (h2 + 252) & 255;
  const int wh = th >> 3, wi = th & 7;
  const int tid = threadIdx.x;
  const int wv = tid >> 6, l = tid & 63, lr = l & 15, lg = l >> 4;
  const f4v fz = {0.f,0.f,0.f,0.f};
  const float sH = posH ? 0.5f : -0.5f;
  const long wrow0 = (long)(b*1024 + wh*32);

  // per-thread column constants (cols = nt*16+lr)
  float amv[12], cvv[12], pbv[12];
#pragma unroll
  for (int nt = 0; nt < 12; ++nt){
    const int col = nt*16 + lr;
    amv[nt] = amul[b*192 + col];
    cvv[nt] = cval[b*192 + col];
    pbv[nt] = pf[P_PROJB + col];
  }

#pragma unroll
  for (int ck = 0; ck < 2; ++ck){
    const int w2base = half*128 + ck*64;
    // stage hraw rows r=0..63 (w2 = w2base + r), linear dest + inverse-swizzled source
#pragma unroll
    for (int pass = 0; pass < 6; ++pass){
      const int idx = pass*256 + tid;               // 16B unit 0..1535
      const int r   = idx / 24;
      const int off = (idx - r*24) * 16;
      const int soff = off ^ ((r & 7) << 4);
      const int tw = (w2base + r + 252) & 255;
      const long src = (wrow0 + (tw >> 3))*12288 + (wi*8 + (tw & 7))*192;
      gld16(hraw + src + (soff >> 1), (char*)hst + (pass*256 + wv*64)*16);
    }
    // A-fragment row for this lane
    const int rA = wv*16 + lr;
    const int twA = (w2base + rA + 252) & 255;
    const bf16* arow = wout + (wrow0 + (twA >> 3))*12288 + (wi*8 + (twA & 7))*192;
    s8v aA[6];
#pragma unroll
    for (int ks = 0; ks < 6; ++ks)
      aA[ks] = *(const s8v*)(arow + ks*32 + lg*8);
    __syncthreads();   // DMA + A loads drained; hst ready

    // proj MFMA: 16 rows x 192 cols
    f4v acc[12];
#pragma unroll
    for (int nt = 0; nt < 12; ++nt) acc[nt] = fz;
#pragma unroll
    for (int ks = 0; ks < 6; ++ks){
      const int k0 = ks*32;
#pragma unroll
      for (int nt = 0; nt < 12; ++nt){
        const s8v bfr = *(const s8v*)(wproj + (nt*16+lr)*192 + k0 + lg*8);
        acc[nt] = MFMA16(aA[ks], bfr, acc[nt]);
      }
    }
    // combine + IWT + yp write
#pragma unroll
    for (int i = 0; i < 4; ++i){
      const int rowo = wv*16 + lg*4 + i;            // chunk-local row
      const int tw2 = (w2base + rowo + 252) & 255;
      const long dlb = ((wrow0 + (tw2 >> 3))*64 + wi*8 + (tw2 & 7))*64;
      const int p0 = ck*128 + 2*rowo;
      const int sw0 = (p0 & 7) << 4, sw1 = ((p0+1) & 7) << 4;
#pragma unroll
      for (int nt2 = 0; nt2 < 4; ++nt2){
        const int c = nt2*16 + lr;
        const int hb = rowo*384;
        const int rsw = (rowo & 7) << 4;
        const float hv0 = bfu(*(const unsigned short*)((const char*)hst + hb + ((c*2) ^ rsw)));
        const float hv1 = bfu(*(const unsigned short*)((const char*)hst + hb + (((64+c)*2) ^ rsw)));
        const float hv2 = bfu(*(const unsigned short*)((const char*)hst + hb + (((128+c)*2) ^ rsw)));
        const float dvc  = amv[nt2]  *(acc[nt2][i]  + pbv[nt2])   + cvv[nt2]  *hv0;
        const float dv64 = amv[nt2+4]*(acc[nt2+4][i]+ pbv[nt2+4]) + cvv[nt2+4]*hv1;
        const float dv128= amv[nt2+8]*(acc[nt2+8][i]+ pbv[nt2+8]) + cvv[nt2+8]*hv2;
        const float dl = __bfloat162float(dllw[dlb + c]);
        const float common = 0.5f*dl + sH*dv64;
        const float e0 = common - 0.5f*dvc - sH*dv128;
        const float e1 = common + 0.5f*dvc + sH*dv128;
        *(bf16*)(ypb + ((p0*128     + c*2) ^ sw0)) = __float2bfloat16(e0);
        *(bf16*)(ypb + (((p0+1)*128 + c*2) ^ sw1)) = __float2bfloat16(e1);
      }
    }
    __syncthreads();   // yp chunk written; hst free for next chunk
  }

  // out-conv MFMA + coalesced store (pixels px0 + [0,64) per wave)
  f4v acc2[4][4];
#pragma unroll
  for (int mt = 0; mt < 4; ++mt)
#pragma unroll
    for (int nt = 0; nt < 4; ++nt) acc2[mt][nt] = fz;
#pragma unroll
  for (int ks = 0; ks < 2; ++ks){
    const int k0 = ks*32;
    s8v a[4];
#pragma unroll
    for (int mt = 0; mt < 4; ++mt)
      a[mt] = *(const s8v*)(wpo + (mt*16+lr)*64 + k0 + lg*8);
#pragma unroll
    for (int nt = 0; nt < 4; ++nt){
      const int prow = wv*64 + nt*16 + lr;
      const s8v bfr = *(const s8v*)(ypb + ((prow*128 + (k0+lg*8)*2) ^ ((prow&7)<<4)));
#pragma unroll
      for (int mt = 0; mt < 4; ++mt) acc2[mt][nt] = MFMA16(a[mt], bfr, acc2[mt][nt]);
    }
  }
  const int px0 = half*256 + wv*64;
#pragma unroll
  for (int mt = 0; mt < 4; ++mt)
#pragma unroll
    for (int nt = 0; nt < 4; ++nt)
#pragma unroll
      for (int i = 0; i < 4; ++i){
        const int c = mt*16 + lg*4 + i;
        const long ob = ((long)(b*64 + c)*512 + hh)*512 + px0 + nt*16 + lr;
        ST<ISF>(out, ob, acc2[mt][nt][i]);
      }
}
__global__ __launch_bounds__(256,2) void k57_out(const bf16* wout, const bf16* hraw,
                                                 const bf16* dllw, const bf16* wproj,
                                                 const bf16* wpo, const float* pf,
                                                 const float* amul, const float* cval,
                                                 void* out, const int* flag){
  __shared__ __align__(16) char sm[57344];
  if (*flag) k57_body<true>(wout, hraw, dllw, wproj, wpo, pf, amul, cval, out, sm);
  else       k57_body<false>(wout, hraw, dllw, wproj, wpo, pf, amul, cval, out, sm);
}

// ---------------- launcher ----------------
extern "C" void kernel_launch(void* const* d_in, const int* in_sizes, int n_in,
                              void* d_out, int out_size, void* d_ws, size_t ws_size,
                              hipStream_t stream){
  char* ws = (char*)d_ws;
  int*   flag = (int*)(ws + WS_FLAG);
  float* pf   = (float*)(ws + WS_PARAMS);
  float* gap  = (float*)(ws + WS_GAP);
  float* amul = (float*)(ws + WS_AMUL);
  float* cval = (float*)(ws + WS_CVAL);
  float2* tstat=(float2*)(ws + WS_TSTAT);
  bf16*  llb  = (bf16*)(ws + WS_LL);
  bf16*  dllw = (bf16*)(ws + WS_DLLW);
  bf16*  wout = (bf16*)(ws + WS_WOUT);
  bf16*  hraw = (bf16*)(ws + WS_HRAW);
  bf16*  wqkvF= (bf16*)(ws + WS_WQKV);
  bf16*  wproj= (bf16*)(ws + WS_WPROJ);
  bf16*  wpw  = (bf16*)(ws + WS_WPW);
  bf16*  wpo  = (bf16*)(ws + WS_WPO);
  float2* s12p= (float2*)(ws + WS_S12);
  float* bias6= (float*)(ws + WS_BIAS6);
  const int* rpi = (const int*)d_in[16];

  detect_kernel<<<1, 256, 0, stream>>>(d_in[0], flag);

  PP pp;
  const int pidx[15] = {1,2,3,4,5,6,7,8,9,10,11,12,13,14,15};
  const int poff[15] = {P_NORMW,P_NORMB,P_QKVW,P_QKVB,P_PROJW,P_PROJB,P_RPB,
                        P_AUXDW,P_AUXPW,P_CG1,P_CG2,P_PO,P_GM,P_GA,P_GC};
  for (int q = 0; q < 15; q++){
    pp.src[q] = d_in[pidx[q]];
    pp.dst[q] = pf + poff[q];
    pp.n[q]   = in_sizes[pidx[q]];
  }
  kprep<<<512, 256, 0, stream>>>(pp, flag, rpi, wqkvF, wproj, wpw, wpo, bias6, s12p);

  k1f_dwt<<<NWIN, 256, 0, stream>>>(d_in[0], llb, hraw, tstat, flag);
  kmix   <<<7296, 512, 0, stream>>>(hraw, tstat, wqkvF, s12p, bias6, wout,
                                    llb, pf, wpw, dllw, gap);
  k3_cross<<<1,   256, 0, stream>>>(pf, gap, amul, cval);
  k57_out<<<2048, 256, 0, stream>>>(wout, hraw, dllw, wproj, wpo, pf,
                                    amul, cval, d_out, flag);
}

// Round 16
// 378.970 us; speedup vs baseline: 1.3949x; 1.3949x over previous
//
#include <hip/hip_runtime.h>
#include <hip/hip_bf16.h>
#include <math.h>

typedef __hip_bfloat16 bf16;
typedef short s8v __attribute__((ext_vector_type(8)));
typedef float f4v __attribute__((ext_vector_type(4)));
#define MFMA16(a,b,c) __builtin_amdgcn_mfma_f32_16x16x32_bf16(a,b,c,0,0,0)

// ---------------- problem constants ----------------
#define B2   2
#define C64  64
#define C3   192
#define HEADS 6
#define NWIN 2048   // 2 * 32 * 32 windows

// ---------------- param table offsets (floats) ----------------
#define P_NORMW 0
#define P_NORMB 192
#define P_QKVW  384
#define P_QKVB  110976
#define P_PROJW 111552
#define P_PROJB 148416
#define P_RPB   148608
#define P_AUXDW 149958
#define P_AUXPW 150534
#define P_CG1   154630
#define P_CG2   157702
#define P_PO    166918
#define P_GM    171014
#define P_GA    171015
#define P_GC    171016

// ---------------- workspace byte offsets ----------------
#define WS_FLAG   0
#define WS_PARAMS 256
#define WS_GAP    684544
#define WS_AMUL   685568
#define WS_CVAL   687616
#define WS_TSTAT  689664                   // float2 [2048*64]
#define WS_LL     1738240                  // bf16 [2][64][256][256]
#define WS_DLLW   18515456                 // bf16 [2048][64][64]  (window layout)
#define WS_WOUT   35292672                 // bf16 [2048][64][192] (-> dval in place)
#define WS_HRAW   85624320                 // bf16 [2048][64][192]
#define WS_WQKV   135955968                // bf16 [576][192]  (LN-folded)
#define WS_WPROJ  136177152                // bf16 [192][192]
#define WS_WPW    136250880                // bf16 [64][64]
#define WS_WPO    136259072                // bf16 [64][64]
#define WS_S12    136267264                // float2 [576] (s1, s2+bias)
#define WS_BIAS6  136271872                // f32 [6][64col][64row] (transposed)
// end = 136,370,176  (< 168.5 MB proven)

// ---------------- helpers ----------------
__device__ __forceinline__ float bfu(unsigned short u){
  return __uint_as_float(((unsigned)u) << 16);
}
__device__ __forceinline__ float LDR(const void* p, long i, bool isf){
  return isf ? ((const float*)p)[i] : bfu(((const unsigned short*)p)[i]);
}
template<bool ISF>
__device__ __forceinline__ float4 LD4(const void* p, long i){   // elems i..i+3 (i%4==0 fp32)
  if constexpr (ISF) return *(const float4*)((const float*)p + i);
  else {
    const ushort4 u = *(const ushort4*)((const bf16*)p + i);
    float4 r; r.x = bfu(u.x); r.y = bfu(u.y); r.z = bfu(u.z); r.w = bfu(u.w);
    return r;
  }
}
template<bool ISF>
__device__ __forceinline__ void ST(void* p, long i, float v){
  if constexpr (ISF) ((float*)p)[i] = v;
  else ((bf16*)p)[i] = __float2bfloat16(v);
}
__device__ __forceinline__ float gelu_f(float x){
  const float z = 0.7978845608028654f * (x + 0.044715f * x*x*x);
  const float t = 1.f - 2.f / (__expf(2.f*z) + 1.f);
  return 0.5f * x * (1.f + t);
}
__device__ __forceinline__ unsigned pk2(float a, float b){
  return (unsigned)__bfloat16_as_ushort(__float2bfloat16(a)) |
         ((unsigned)__bfloat16_as_ushort(__float2bfloat16(b)) << 16);
}
__device__ __forceinline__ uint4 pk8(const float* v){
  uint4 r;
  r.x = pk2(v[0], v[1]); r.y = pk2(v[2], v[3]);
  r.z = pk2(v[4], v[5]); r.w = pk2(v[6], v[7]);
  return r;
}
// async global->LDS 16B DMA: dest = wave-uniform base + lane*16
__device__ __forceinline__ void gld16(const void* g, void* l){
  __builtin_amdgcn_global_load_lds(
      (const __attribute__((address_space(1))) void*)g,
      (__attribute__((address_space(3))) void*)l, 16, 0, 0);
}

// ---------------- K0a: dtype detect ----------------
__global__ __launch_bounds__(256) void detect_kernel(const void* x, int* flag){
  __shared__ int wildcnt;
  if (threadIdx.x == 0) wildcnt = 0;
  __syncthreads();
  const unsigned short* u = (const unsigned short*)x;
  int wild = 0;
  for (int i = threadIdx.x; i < 2048; i += 256){
    unsigned int v = ((unsigned int)u[i]) << 16;
    float f = __uint_as_float(v);
    float a = fabsf(f);
    if (!(a < 1e8f) || (a > 0.f && a < 1e-8f)) wild++;
  }
  atomicAdd(&wildcnt, wild);
  __syncthreads();
  if (threadIdx.x == 0) *flag = (wildcnt > 100) ? 1 : 0;  // 1 = fp32 underlying
}

// ---------------- prep body (param convert + weight tables), 512 virtual blocks ----------------
struct PP { const void* src[15]; float* dst[15]; int n[15]; };
__device__ void kprep_body(int vblk, const PP& pp, bool isf, const int* rpi,
                           bf16* wqkvF, bf16* wproj, bf16* wpw,
                           bf16* wpo, float* bias6T, float2* s12p){
  const int gid = vblk*256 + threadIdx.x;
  const int gsz = 512*256;
#pragma unroll
  for (int q = 0; q < 15; q++){
    const int n = pp.n[q];
    const void* s = pp.src[q];
    float* d = pp.dst[q];
    for (int i = gid; i < n; i += gsz) d[i] = LDR(s, i, isf);
  }
  const void* qkvw = pp.src[2];
  const void* normw = pp.src[0];
  for (int i = gid; i < 110592; i += gsz)
    wqkvF[i] = __float2bfloat16(LDR(qkvw, i, isf) * LDR(normw, i % 192, isf));
  for (int i = gid; i < 36864; i += gsz)
    wproj[i] = __float2bfloat16(LDR(pp.src[4], i, isf));
  for (int i = gid; i < 4096; i += gsz){
    wpw[i] = __float2bfloat16(LDR(pp.src[8], i, isf));
    wpo[i] = __float2bfloat16(LDR(pp.src[11], i, isf));
  }
  for (int j = gid; j < 24576; j += gsz){
    const int hh = j >> 12, nm = j & 4095;
    const int row = nm >> 6, col = nm & 63;
    bias6T[hh*4096 + col*64 + row] = LDR(pp.src[6], rpi[nm]*6 + hh, isf);
  }
  // rank-1 LN correction, 16-lane groups
  const int o = gid >> 4, lane = gid & 15;
  if (o < 576){
    float s1 = 0.f, s2 = 0.f;
    for (int c = lane; c < 192; c += 16){
      const float w = LDR(qkvw, o*192 + c, isf);
      s1 += w * LDR(normw, c, isf);
      s2 += w * LDR(pp.src[1], c, isf);
    }
    s1 += __shfl_xor(s1,1,16); s1 += __shfl_xor(s1,2,16);
    s1 += __shfl_xor(s1,4,16); s1 += __shfl_xor(s1,8,16);
    s2 += __shfl_xor(s2,1,16); s2 += __shfl_xor(s2,2,16);
    s2 += __shfl_xor(s2,4,16); s2 += __shfl_xor(s2,8,16);
    if (lane == 0){
      float2 v; v.x = s1; v.y = s2 + LDR(pp.src[3], o, isf);
      s12p[o] = v;
    }
  }
}

// ---------------- k1f body: single-pass DWT (16B loads) -> ll + hraw + tstat ----------------
template<bool ISF>
__device__ void k1f_body(int wid, const void* xv, bf16* llb, bf16* hraw, float2* tstat){
  const int b  = wid >> 10;
  const int wh = (wid >> 5) & 31;
  const int ww = wid & 31;
  const int tid = threadIdx.x;
  const int tp = tid >> 3, l8 = tid & 7;   // token pair 0..31, channel group 0..7
  const int t0 = tp*2;
  const int wi = t0 >> 3, wj0 = t0 & 7;    // wj0 even
  const int h2 = (wh*8 + wi + 4) & 255;
  const int w2 = (ww*8 + wj0 + 4) & 255;   // even
  const long rowbase = ((long)(2*h2) << 9) + 2*w2;
  float r0[3][8], r1[3][8];
  float s0 = 0.f, q0 = 0.f, s1 = 0.f, q1 = 0.f;
#pragma unroll
  for (int cc = 0; cc < 8; ++cc){
    const int c = l8*8 + cc;
    const long base = ((long)(b*64 + c) << 18) + rowbase;
    const float4 ta = LD4<ISF>(xv, base);        // a0,cr0,a1,cr1
    const float4 tb = LD4<ISF>(xv, base + 512);  // bb0,dd0,bb1,dd1
    float a = ta.x, cr = ta.y, bb = tb.x, dd = tb.y;
    const float ll0 = 0.5f*(a + bb + cr + dd);
    const float h00 = 0.5f*(-a - bb + cr + dd);
    const float h10 = 0.5f*(-a + bb - cr + dd);
    const float h20 = 0.5f*( a - bb - cr + dd);
    r0[0][cc] = h00; r0[1][cc] = h10; r0[2][cc] = h20;
    s0 += h00 + h10 + h20; q0 += h00*h00 + h10*h10 + h20*h20;
    a = ta.z; cr = ta.w; bb = tb.z; dd = tb.w;
    const float ll1 = 0.5f*(a + bb + cr + dd);
    const float h01 = 0.5f*(-a - bb + cr + dd);
    const float h11 = 0.5f*(-a + bb - cr + dd);
    const float h21 = 0.5f*( a - bb - cr + dd);
    r1[0][cc] = h01; r1[1][cc] = h11; r1[2][cc] = h21;
    s1 += h01 + h11 + h21; q1 += h01*h01 + h11*h11 + h21*h21;
    *(unsigned*)(llb + ((long)(b*64 + c) << 16) + ((long)h2 << 8) + w2) = pk2(ll0, ll1);
  }
  const long hb = ((long)wid*64 + t0)*192 + l8*8;
  *(uint4*)(hraw + hb)            = pk8(r0[0]);
  *(uint4*)(hraw + hb + 64)       = pk8(r0[1]);
  *(uint4*)(hraw + hb + 128)      = pk8(r0[2]);
  *(uint4*)(hraw + hb + 192)      = pk8(r1[0]);
  *(uint4*)(hraw + hb + 192 + 64) = pk8(r1[1]);
  *(uint4*)(hraw + hb + 192 +128) = pk8(r1[2]);
  s0 += __shfl_xor(s0,1,8); s0 += __shfl_xor(s0,2,8); s0 += __shfl_xor(s0,4,8);
  q0 += __shfl_xor(q0,1,8); q0 += __shfl_xor(q0,2,8); q0 += __shfl_xor(q0,4,8);
  s1 += __shfl_xor(s1,1,8); s1 += __shfl_xor(s1,2,8); s1 += __shfl_xor(s1,4,8);
  q1 += __shfl_xor(q1,1,8); q1 += __shfl_xor(q1,2,8); q1 += __shfl_xor(q1,4,8);
  if (l8 == 0){
    float mean = s0 * (1.f/192.f);
    float var = fmaxf(q0 * (1.f/192.f) - mean*mean, 0.f);
    float rstd = rsqrtf(var + 1e-6f);
    float2 st; st.x = rstd; st.y = mean * rstd;
    tstat[wid*64 + t0] = st;
    mean = s1 * (1.f/192.f);
    var = fmaxf(q1 * (1.f/192.f) - mean*mean, 0.f);
    rstd = rsqrtf(var + 1e-6f);
    st.x = rstd; st.y = mean * rstd;
    tstat[wid*64 + t0 + 1] = st;
  }
}

// ---------------- K1P: fused DWT + prep (independent work, one launch) ----------------
__global__ __launch_bounds__(256,4) void k1p(const void* xv, bf16* llb, bf16* hraw,
                                             float2* tstat, const int* flag, PP pp,
                                             const int* rpi, bf16* wqkvF, bf16* wproj,
                                             bf16* wpw, bf16* wpo, float* bias6T,
                                             float2* s12p){
  const bool isf = (*flag) != 0;
  const int blk = blockIdx.x;
  if (blk < NWIN){
    if (isf) k1f_body<true>(blk, xv, llb, hraw, tstat);
    else     k1f_body<false>(blk, xv, llb, hraw, tstat);
  } else {
    kprep_body(blk - NWIN, pp, isf, rpi, wqkvF, wproj, wpw, wpo, bias6T, s12p);
  }
}

// ---------------- K3: cross MLP ----------------
__global__ __launch_bounds__(256) void k3_cross(const float* pf, const float* gap,
                                                float* amul, float* cval){
  __shared__ float t1[B2][48];
  __shared__ float g[B2][64];
  const int tid = threadIdx.x;
  if (tid < 128) g[tid >> 6][tid & 63] = gap[tid];
  __syncthreads();
  if (tid < 96){
    const int b = tid / 48, j = tid % 48;
    float s = 0.f;
    const float* w = pf + P_CG1 + j * 64;
    for (int c = 0; c < 64; ++c) s += w[c] * g[b][c];
    t1[b][j] = gelu_f(s);
  }
  __syncthreads();
  const float gm = pf[P_GM], gc = pf[P_GC];
  for (int o = tid; o < B2 * C3; o += 256){
    const int b = o / C3, ch = o % C3;
    float s = 0.f;
    const float* w = pf + P_CG2 + ch * 48;
    for (int j = 0; j < 48; ++j) s += w[j] * t1[b][j];
    const float cr = 1.f / (1.f + expf(-s));
    const float c = gc * (cr - 0.5f) * 2.f;
    cval[o] = c;
    amul[o] = gm * (1.f + c);
  }
}

// ================= KMIX: interleaved k4 attention + k6f aux-conv + k2 gap =================
__device__ void k4_body(char* sm, int g, const bf16* hraw, const float2* tstat,
                        const bf16* wqkvF, const float2* s12p, const float* bias6T,
                        bf16* wout){
  bf16* bstage = (bf16*)sm;
  const int xcd = g & 7, slot = g >> 3;
  const int pair = (slot/6)*8 + xcd;
  const int h    = slot - (slot/6)*6;
  const int tid = threadIdx.x;
  const int wv5 = tid >> 6;             // 0..7
  const int lw  = wv5 >> 2;             // local window
  const int rg  = wv5 & 3;              // row group
  const int l = tid & 63, lr = l & 15, lg = l >> 4;
  const int wid = pair*2 + lw;
  char* reg = sm + 36864 + lw*13312;
  bf16* bq = (bf16*)reg;
  bf16* bk = (bf16*)(reg + 4608);
  char* vtb = reg + 9216;
  bf16* bp = (bf16*)reg;
  const f4v fz = {0.f,0.f,0.f,0.f};
  const float scale = 0.17677669529663687f;
  const bf16* at = hraw + (long)wid * 12288;

#pragma unroll
  for (int pass = 0; pass < 5; ++pass){
    if (pass*512 + wv5*64 < 2304){
      const int idx = pass*512 + tid;
      const int rl  = idx / 24;
      const int off = (idx - rl*24) * 16;
      const int soff = off ^ ((rl & 7) << 4);
      const int grow = (rl >> 5)*192 + h*32 + (rl & 31);
      gld16(wqkvF + grow*192 + (soff >> 1),
            (char*)bstage + (pass*512 + wv5*64)*16);
    }
  }
  s8v aA[6];
#pragma unroll
  for (int ks = 0; ks < 6; ++ks)
    aA[ks] = *(const s8v*)(at + (rg*16+lr)*192 + ks*32 + lg*8);
  float2 st4[4];
#pragma unroll
  for (int i = 0; i < 4; ++i)
    st4[i] = tstat[wid*64 + rg*16 + lg*4 + i];
  __syncthreads();

  f4v acc[6];
#pragma unroll
  for (int nt = 0; nt < 6; ++nt) acc[nt] = fz;
#pragma unroll
  for (int ks = 0; ks < 6; ++ks){
    const int kb = (ks*32 + lg*8) * 2;
#pragma unroll
    for (int nt = 0; nt < 6; ++nt){
      const int row = nt*16 + lr;
      const s8v bfr = *(const s8v*)((const char*)bstage + row*384 + (kb ^ ((row&7)<<4)));
      acc[nt] = MFMA16(aA[ks], bfr, acc[nt]);
    }
  }
#pragma unroll
  for (int nt = 0; nt < 6; ++nt){
    const int ol = nt*16 + lr;
    const int p = ol >> 5, c = ol & 31;
    const int ocol = p*192 + h*32 + c;
    const float2 sp = s12p[ocol];
#pragma unroll
    for (int i = 0; i < 4; ++i){
      const int row = rg*16 + lg*4 + i;
      const float v = st4[i].x*acc[nt][i] - st4[i].y*sp.x + sp.y;
      if (p == 0)      bq[row*36 + c] = __float2bfloat16(v*scale);
      else if (p == 1) bk[row*36 + c] = __float2bfloat16(v);
      else             *(bf16*)(vtb + ((c*128 + row*2) ^ ((c&7)<<4))) = __float2bfloat16(v);
    }
  }
  __syncthreads();

  f4v bld[4];
#pragma unroll
  for (int nt = 0; nt < 4; ++nt)
    bld[nt] = *(const f4v*)(bias6T + h*4096 + (nt*16+lr)*64 + rg*16 + lg*4);
  f4v sacc[4];
  {
    const s8v a = *(const s8v*)(bq + (rg*16+lr)*36 + lg*8);
#pragma unroll
    for (int nt = 0; nt < 4; ++nt){
      const s8v bfr = *(const s8v*)(bk + (nt*16+lr)*36 + lg*8);
      sacc[nt] = MFMA16(a, bfr, bld[nt]);   // bias folded into C operand
    }
  }
  float pvv[4][4];
  float inv4[4];
#pragma unroll
  for (int i = 0; i < 4; ++i){
    float s = 0.f;
#pragma unroll
    for (int nt = 0; nt < 4; ++nt){
      const float e = __expf(sacc[nt][i]);
      pvv[i][nt] = e;
      s += e;
    }
    s += __shfl_xor(s, 1, 16);
    s += __shfl_xor(s, 2, 16);
    s += __shfl_xor(s, 4, 16);
    s += __shfl_xor(s, 8, 16);
    inv4[i] = 1.f/s;
  }
  __syncthreads();

#pragma unroll
  for (int i = 0; i < 4; ++i){
    const int row = rg*16 + lg*4 + i;
#pragma unroll
    for (int nt = 0; nt < 4; ++nt)
      bp[row*72 + nt*16 + lr] = __float2bfloat16(pvv[i][nt]);
  }
  f4v oacc[2] = {fz, fz};
#pragma unroll
  for (int ks2 = 0; ks2 < 2; ++ks2){
    const s8v a = *(const s8v*)(bp + (rg*16+lr)*72 + ks2*32 + lg*8);
#pragma unroll
    for (int nn = 0; nn < 2; ++nn){
      const int d = nn*16 + lr;
      const s8v bfr = *(const s8v*)(vtb + ((d*128 + (ks2*32+lg*8)*2) ^ ((d&7)<<4)));
      oacc[nn] = MFMA16(a, bfr, oacc[nn]);
    }
  }
#pragma unroll
  for (int nn = 0; nn < 2; ++nn)
#pragma unroll
    for (int i = 0; i < 4; ++i){
      const int row = rg*16 + lg*4 + i;
      wout[((long)wid*64 + row)*192 + h*32 + nn*16 + lr] =
        __float2bfloat16(oacc[nn][i] * inv4[i]);
    }
}

__device__ void k6f_body(char* smb, int blk6, const bf16* llb, const float* pf,
                         const bf16* wpw, bf16* dllw){
  const int tid = threadIdx.x;
  const int sub = tid >> 8;              // 0..1
  const int t2 = tid & 255;
  char* sm6 = smb + sub*24576;
  bf16* tile = (bf16*)sm6;               // [64][10][12]
  bf16* t    = (bf16*)(sm6 + 15360);     // [64][72]
  const int tl = blk6*2 + sub;
  const int b = tl >> 10, ti = (tl >> 5) & 31, tj = tl & 31;
  const int y0 = ti*8 - 1;
  const int x0 = tj*8 - 2;

  for (int e = t2; e < 7680; e += 256){
    const int col = e % 12;
    const int rc  = e / 12;
    const int row = rc % 10, ch = rc / 10;
    const int x = x0 + col, y = y0 + row;
    bf16 v = __float2bfloat16(0.f);
    if ((unsigned)x < 256u && (unsigned)y < 256u)
      v = llb[((long)(b*64 + ch) << 16) + ((long)y << 8) + x];
    tile[rc*12 + col] = v;
  }
  __syncthreads();

  {
    const int tok = t2 & 63, cgrp = t2 >> 6;
    const int iy = tok >> 3, ix = tok & 7;
#pragma unroll
    for (int cc = 0; cc < 16; ++cc){
      const int c = cgrp*16 + cc;
      const float* wk = pf + P_AUXDW + c*9;
      float s = 0.f;
#pragma unroll
      for (int ky = 0; ky < 3; ++ky)
#pragma unroll
        for (int kx = 0; kx < 3; ++kx)
          s += wk[ky*3 + kx] * __bfloat162float(tile[(c*10 + iy + ky)*12 + ix + 1 + kx]);
      t[tok*72 + c] = __float2bfloat16(gelu_f(s));
    }
  }
  __syncthreads();

  const int wv = t2 >> 6, l = t2 & 63, lr = l & 15, lg = l >> 4;
  const f4v fz = {0.f,0.f,0.f,0.f};
  f4v acc[4];
#pragma unroll
  for (int nt = 0; nt < 4; ++nt) acc[nt] = fz;
#pragma unroll
  for (int ks = 0; ks < 2; ++ks){
    const s8v a = *(const s8v*)(t + (wv*16+lr)*72 + ks*32 + lg*8);
#pragma unroll
    for (int nt = 0; nt < 4; ++nt){
      const s8v bfr = *(const s8v*)(wpw + (nt*16+lr)*64 + ks*32 + lg*8);
      acc[nt] = MFMA16(a, bfr, acc[nt]);
    }
  }
  const float ga = pf[P_GA];
#pragma unroll
  for (int i = 0; i < 4; ++i){
    const int p = wv*16 + lg*4 + i;
    const int y = ti*8 + (p >> 3), x = tj*8 + (p & 7);
    const int sy = (y - 4) & 255, sx = (x - 4) & 255;
    const int wd = b*1024 + (sy >> 3)*32 + (sx >> 3);
    const int tok2 = (sy & 7)*8 + (sx & 7);
    const long ob = ((long)wd*64 + tok2)*64;
#pragma unroll
    for (int nt = 0; nt < 4; ++nt)
      dllw[ob + nt*16 + lr] = __float2bfloat16(ga * acc[nt][i]);
  }
}

__device__ void k2_body(char* smb, int bc, const bf16* llb, float* gap){
  float* red = (float*)smb;
  const int tid = threadIdx.x;
  const uint4* p = (const uint4*)(llb + ((long)bc << 16));
  float s = 0.f;
  for (int i = tid; i < 8192; i += 512){
    const uint4 v = p[i];
    s += __uint_as_float(v.x << 16) + __uint_as_float(v.x & 0xffff0000u);
    s += __uint_as_float(v.y << 16) + __uint_as_float(v.y & 0xffff0000u);
    s += __uint_as_float(v.z << 16) + __uint_as_float(v.z & 0xffff0000u);
    s += __uint_as_float(v.w << 16) + __uint_as_float(v.w & 0xffff0000u);
  }
  red[tid] = s; __syncthreads();
  for (int st = 256; st > 0; st >>= 1){
    if (tid < st) red[tid] += red[tid + st];
    __syncthreads();
  }
  if (tid == 0) gap[bc] = red[0] * (1.f / 65536.f);
}

__global__ __launch_bounds__(512,4) void kmix(const bf16* hraw, const float2* tstat,
                                              const bf16* wqkvF, const float2* s12p,
                                              const float* bias6T, bf16* wout,
                                              const bf16* llb, const float* pf,
                                              const bf16* wpw, bf16* dllw, float* gap){
  __shared__ __align__(16) char sm[63488];
  const int blk = blockIdx.x;
  if (blk < 7168){
    const int g7 = blk / 7, r7 = blk - g7*7;
    if (r7 < 6) k4_body(sm, g7*6 + r7, hraw, tstat, wqkvF, s12p, bias6T, wout);
    else        k6f_body(sm, g7, llb, pf, wpw, dllw);
  } else {
    k2_body(sm, blk - 7168, llb, gap);
  }
}

// ---------------- K5: proj MFMA (A direct) + combine; hraw staged via global_load_lds ----------------
__global__ __launch_bounds__(256,5) void k5_proj(bf16* wout, const bf16* hraw,
                                                 const bf16* wproj, const float* pf,
                                                 const float* amul, const float* cval){
  __shared__ __align__(16) bf16 bufC[64*192];   // hraw tile, swizzled content
  const int wid = blockIdx.x;
  const int b  = wid >> 10;
  const int tid = threadIdx.x;
  const int wv = tid >> 6, l = tid & 63, lr = l & 15, lg = l >> 4;

  {
    const bf16* hsrc = hraw + (long)wid * 12288;
#pragma unroll
    for (int pass = 0; pass < 6; ++pass){
      const int idx = pass*256 + tid;               // 16B unit 0..1535
      const int row = idx / 24;
      const int off = (idx % 24) * 16;
      const int soff = off ^ ((row & 7) << 4);
      gld16(hsrc + row*192 + (soff >> 1),
            (char*)bufC + (pass*256 + wv*64)*16);
    }
  }

  const f4v fz = {0.f,0.f,0.f,0.f};
  const bf16* at = wout + (long)wid * 12288;

  f4v acc[3][4];
#pragma unroll
  for (int nt = 0; nt < 3; ++nt)
#pragma unroll
    for (int mt = 0; mt < 4; ++mt) acc[nt][mt] = fz;
#pragma unroll
  for (int ks = 0; ks < 6; ++ks){
    const int k0 = ks*32;
    s8v a[4];
#pragma unroll
    for (int mt = 0; mt < 4; ++mt)
      a[mt] = *(const s8v*)(at + (mt*16+lr)*192 + k0 + lg*8);
#pragma unroll
    for (int nt = 0; nt < 3; ++nt){
      const int ocol = (wv*3+nt)*16 + lr;
      const s8v bfr = *(const s8v*)(wproj + ocol*192 + k0 + lg*8);
#pragma unroll
      for (int mt = 0; mt < 4; ++mt) acc[nt][mt] = MFMA16(a[mt], bfr, acc[nt][mt]);
    }
  }
  __syncthreads();   // DMA + all waves' global A-reads drained before in-place write
#pragma unroll
  for (int nt = 0; nt < 3; ++nt){
    const int col = (wv*3+nt)*16 + lr;
    const int bc = b*192 + col;
    const float am = amul[bc], cv = cval[bc], pb = pf[P_PROJB + col];
#pragma unroll
    for (int mt = 0; mt < 4; ++mt)
#pragma unroll
      for (int i = 0; i < 4; ++i){
        const int row = mt*16 + lg*4 + i;
        const float hv = __bfloat162float(
          *(const bf16*)((const char*)bufC + row*384 + ((col*2) ^ ((row&7)<<4))));
        wout[(long)wid*12288 + row*192 + col] =
          __float2bfloat16(am*(acc[nt][mt][i] + pb) + cv*hv);
      }
  }
}

// ---------------- K7: gather + IWT + out-conv MFMA + coalesced store ----------------
template<bool ISF>
__device__ void k7_body(const bf16* dvalw, const bf16* dllw, const bf16* wpo,
                        void* out, char* yp){
  const int blk = blockIdx.x;
  const int b = blk >> 10, hh = (blk >> 1) & 511, half = blk & 1;
  const int h2 = hh >> 1, posH = hh & 1;
  const int th = (h2 + 252) & 255;
  const int wh = th >> 3, wi = th & 7;
  const int tid = threadIdx.x;
  const int j = tid & 7;
#pragma unroll
  for (int pass = 0; pass < 8; ++pass){
    const int p = pass*32 + (tid >> 3);
    const int ww2 = half*256 + p;
    const int w2 = ww2 >> 1, posW = ww2 & 1;
    const int tw = (w2 + 252) & 255;
    const int ww = tw >> 3, wj = tw & 7;
    const int wid = b*1024 + wh*32 + ww;
    const int tok = wi*8 + wj;
    const long dvb = ((long)wid*64 + tok)*192 + j*8;
    const s8v hl8 = *(const s8v*)(dvalw + dvb);
    const s8v lh8 = *(const s8v*)(dvalw + dvb + 64);
    const s8v hh8 = *(const s8v*)(dvalw + dvb + 128);
    const s8v dl8 = *(const s8v*)(dllw + ((long)wid*64 + tok)*64 + j*8);
    const float s1 = posW ? 0.5f : -0.5f;
    const float s2 = posH ? 0.5f : -0.5f;
    const float s3 = posW == posH ? 0.5f : -0.5f;
    float e[8];
#pragma unroll
    for (int q = 0; q < 8; ++q)
      e[q] = 0.5f*bfu((unsigned short)dl8[q]) + s1*bfu((unsigned short)hl8[q])
           + s2*bfu((unsigned short)lh8[q]) + s3*bfu((unsigned short)hh8[q]);
    *(uint4*)(yp + ((p*128 + j*16) ^ ((p&7)<<4))) = pk8(e);
  }
  __syncthreads();
  const int wv = tid >> 6, l = tid & 63, lr = l & 15, lg = l >> 4;
  const f4v fz = {0.f,0.f,0.f,0.f};
  f4v acc[4][4];
#pragma unroll
  for (int mt = 0; mt < 4; ++mt)
#pragma unroll
    for (int nt = 0; nt < 4; ++nt) acc[mt][nt] = fz;
#pragma unroll
  for (int ks = 0; ks < 2; ++ks){
    const int k0 = ks*32;
    s8v a[4];
#pragma unroll
    for (int mt = 0; mt < 4; ++mt)
      a[mt] = *(const s8v*)(wpo + (mt*16+lr)*64 + k0 + lg*8);
#pragma unroll
    for (int nt = 0; nt < 4; ++nt){
      const int prow = wv*64 + nt*16 + lr;
      const s8v bfr = *(const s8v*)(yp + ((prow*128 + (k0+lg*8)*2) ^ ((prow&7)<<4)));
#pragma unroll
      for (int mt = 0; mt < 4; ++mt) acc[mt][nt] = MFMA16(a[mt], bfr, acc[mt][nt]);
    }
  }
  const int px0 = half*256 + wv*64;
#pragma unroll
  for (int mt = 0; mt < 4; ++mt)
#pragma unroll
    for (int nt = 0; nt < 4; ++nt)
#pragma unroll
      for (int i = 0; i < 4; ++i){
        const int c = mt*16 + lg*4 + i;
        const long ob = ((long)(b*64 + c)*512 + hh)*512 + px0 + nt*16 + lr;
        ST<ISF>(out, ob, acc[mt][nt][i]);
      }
}
__global__ __launch_bounds__(256,4) void k7_out(const bf16* dvalw, const bf16* dllw,
                                                const bf16* wpo, void* out, const int* flag){
  __shared__ __align__(16) char yp[32768];
  if (*flag) k7_body<true>(dvalw, dllw, wpo, out, yp);
  else       k7_body<false>(dvalw, dllw, wpo, out, yp);
}

// ---------------- launcher ----------------
extern "C" void kernel_launch(void* const* d_in, const int* in_sizes, int n_in,
                              void* d_out, int out_size, void* d_ws, size_t ws_size,
                              hipStream_t stream){
  char* ws = (char*)d_ws;
  int*   flag = (int*)(ws + WS_FLAG);
  float* pf   = (float*)(ws + WS_PARAMS);
  float* gap  = (float*)(ws + WS_GAP);
  float* amul = (float*)(ws + WS_AMUL);
  float* cval = (float*)(ws + WS_CVAL);
  float2* tstat=(float2*)(ws + WS_TSTAT);
  bf16*  llb  = (bf16*)(ws + WS_LL);
  bf16*  dllw = (bf16*)(ws + WS_DLLW);
  bf16*  wout = (bf16*)(ws + WS_WOUT);
  bf16*  hraw = (bf16*)(ws + WS_HRAW);
  bf16*  wqkvF= (bf16*)(ws + WS_WQKV);
  bf16*  wproj= (bf16*)(ws + WS_WPROJ);
  bf16*  wpw  = (bf16*)(ws + WS_WPW);
  bf16*  wpo  = (bf16*)(ws + WS_WPO);
  float2* s12p= (float2*)(ws + WS_S12);
  float* bias6= (float*)(ws + WS_BIAS6);
  const int* rpi = (const int*)d_in[16];

  detect_kernel<<<1, 256, 0, stream>>>(d_in[0], flag);

  PP pp;
  const int pidx[15] = {1,2,3,4,5,6,7,8,9,10,11,12,13,14,15};
  const int poff[15] = {P_NORMW,P_NORMB,P_QKVW,P_QKVB,P_PROJW,P_PROJB,P_RPB,
                        P_AUXDW,P_AUXPW,P_CG1,P_CG2,P_PO,P_GM,P_GA,P_GC};
  for (int q = 0; q < 15; q++){
    pp.src[q] = d_in[pidx[q]];
    pp.dst[q] = pf + poff[q];
    pp.n[q]   = in_sizes[pidx[q]];
  }

  k1p    <<<NWIN + 512, 256, 0, stream>>>(d_in[0], llb, hraw, tstat, flag, pp, rpi,
                                          wqkvF, wproj, wpw, wpo, bias6, s12p);
  kmix   <<<7296, 512, 0, stream>>>(hraw, tstat, wqkvF, s12p, bias6, wout,
                                    llb, pf, wpw, dllw, gap);
  k3_cross<<<1,   256, 0, stream>>>(pf, gap, amul, cval);
  k5_proj<<<NWIN, 256, 0, stream>>>(wout, hraw, wproj, pf, amul, cval);
  k7_out <<<2048, 256, 0, stream>>>(wout, dllw, wpo, d_out, flag);
}